// Round 14
// baseline (743.453 us; speedup 1.0000x reference)
//
#include <hip/hip_runtime.h>
#include <cstdint>
#include <cstddef>

typedef __bf16 bf16;
typedef float f32x4 __attribute__((ext_vector_type(4)));
typedef bf16  bf16x4 __attribute__((ext_vector_type(4)));
typedef bf16  bf16x8 __attribute__((ext_vector_type(8)));

#define DIMD   2048
#define HEADS  32
#define DH     64
#define FFI    8192
#define FUSEDN 18560
#define FUSEDP 18688   // padded to 146*128
#define BB     2
#define NN     2048
#define MROWS  4096   // BB*NN
#define K2     10240  // DIMD + FFI
#define G1TILES 4672  // (FUSEDP/128)*(MROWS/128)

// async global->LDS, 16B per lane, wave-uniform LDS base
__device__ __forceinline__ void gl_lds16(const void* g, void* l) {
  __builtin_amdgcn_global_load_lds(
      (__attribute__((address_space(1))) void*)const_cast<void*>(g),
      (__attribute__((address_space(3))) void*)l, 16, 0, 0);
}

// Stage one gl_lds instruction of a [rows][64] bf16 tile into LDS.
// LDS dest linear (gl_lds constraint); T2 swizzle applied on the GLOBAL
// source: LDS chunk (row, c) receives global chunk (row, c^(row&7)).
template <int THREADS>
__device__ __forceinline__ void stage_i(const bf16* g, long ldk,
                                        bf16* region, int instr, int tid) {
  int row = instr * (THREADS / 8) + (tid >> 3);
  int cs  = (tid & 7) ^ (row & 7);
  gl_lds16(g + (size_t)row * ldk + cs * 8,
           region + (size_t)instr * (THREADS * 8) + (size_t)(tid & ~63) * 8);
}

struct SrcT { const bf16* g; long ldk; };

// ---- m97-style 2-barrier GEMM core: 128x128 tile, BK=64, 256 thr, 32KB LDS ----
template <typename FA, typename FB>
__device__ __forceinline__ void gemm_2ph(FA fa, FB fb, const int NT,
    bf16* As, bf16* Bs, f32x4 (&acc)[4][4],
    const int tid, const int wrow, const int nbase, const int l15, const int h4)
{
  const char* aP[2]; const char* bP[2];
  const int arow = wrow + l15, brow = nbase + l15;
#pragma unroll
  for (int ks = 0; ks < 2; ks++) {
    aP[ks] = (const char*)As + arow * 128 + (((ks * 4 + h4) ^ (arow & 7)) * 16);
    bP[ks] = (const char*)Bs + brow * 128 + (((ks * 4 + h4) ^ (brow & 7)) * 16);
  }
  for (int t = 0; t < NT; ++t) {
    __syncthreads();                       // WAR: all reads of tile t-1 done
    {
      auto a = fa(t); auto b = fb(t);
#pragma unroll
      for (int q = 0; q < 4; q++) stage_i<256>(a.g, a.ldk, As, q, tid);
#pragma unroll
      for (int q = 0; q < 4; q++) stage_i<256>(b.g, b.ldk, Bs, q, tid);
    }
    __syncthreads();                       // full drain: tile t ready
#pragma unroll
    for (int ks = 0; ks < 2; ks++) {
      bf16x8 af[4], bfr[4];
#pragma unroll
      for (int m_ = 0; m_ < 4; m_++) af[m_]  = *(const bf16x8*)(aP[ks] + m_ * 2048);
#pragma unroll
      for (int n_ = 0; n_ < 4; n_++) bfr[n_] = *(const bf16x8*)(bP[ks] + n_ * 2048);
#pragma unroll
      for (int m_ = 0; m_ < 4; m_++)
#pragma unroll
        for (int n_ = 0; n_ < 4; n_++)
          acc[m_][n_] = __builtin_amdgcn_mfma_f32_16x16x32_bf16(af[m_], bfr[n_], acc[m_][n_], 0, 0, 0);
    }
  }
}

// ---------------- fused prep: LN rows + Wf permuted cvt + out zero-init ----------------
__global__ __launch_bounds__(256) void k_prep(const float* __restrict__ x,
                                              const float* __restrict__ g,
                                              bf16* __restrict__ xn,
                                              const float* __restrict__ Wf,
                                              bf16* __restrict__ wfb,
                                              float* __restrict__ out) {
  __shared__ float rs[8];
  const int bid = blockIdx.x, t = threadIdx.x;
  if (bid < MROWS) {
    // ---- LayerNorm row ----
    int row = bid;
    const float4* xr = (const float4*)(x + (size_t)row * DIMD);
    float4 a = xr[t*2], b = xr[t*2+1];
    float s  = a.x+a.y+a.z+a.w + b.x+b.y+b.z+b.w;
    float s2 = a.x*a.x+a.y*a.y+a.z*a.z+a.w*a.w + b.x*b.x+b.y*b.y+b.z*b.z+b.w*b.w;
    for (int o = 1; o < 64; o <<= 1) { s += __shfl_xor(s, o); s2 += __shfl_xor(s2, o); }
    if ((t & 63) == 0) { rs[t>>6] = s; rs[4 + (t>>6)] = s2; }
    __syncthreads();
    s = rs[0]+rs[1]+rs[2]+rs[3]; s2 = rs[4]+rs[5]+rs[6]+rs[7];
    float mu = s * (1.f/DIMD);
    float var = s2 * (1.f/DIMD) - mu*mu;
    float rstd = rsqrtf(var + 1e-5f);
    const float4* gr = (const float4*)g;
    float4 g0 = gr[t*2], g1 = gr[t*2+1];
    bf16x8 o;
    o[0]=(bf16)((a.x-mu)*rstd*g0.x); o[1]=(bf16)((a.y-mu)*rstd*g0.y);
    o[2]=(bf16)((a.z-mu)*rstd*g0.z); o[3]=(bf16)((a.w-mu)*rstd*g0.w);
    o[4]=(bf16)((b.x-mu)*rstd*g1.x); o[5]=(bf16)((b.y-mu)*rstd*g1.y);
    o[6]=(bf16)((b.z-mu)*rstd*g1.z); o[7]=(bf16)((b.w-mu)*rstd*g1.w);
    *(bf16x8*)(xn + (size_t)row * DIMD + t*8) = o;
  } else if (bid < MROWS + 2048) {
    // ---- Wf -> wfb with ff x/gate interleave permutation (grid-stride) ----
    const long total8 = (long)FUSEDN * DIMD / 8;
    const long stride = 2048L * 256;
    for (long i = (long)(bid - MROWS) * 256 + t; i < total8; i += stride) {
      long e = i << 3;
      int p = (int)(e >> 11);
      int c = (int)(e & 2047);
      int orig;
      if (p < 2176) orig = p;
      else {
        int q = p - 2176, gg = q >> 6, o2 = q & 63;
        orig = (o2 < 32) ? (2176 + gg * 32 + o2) : (2176 + 8192 + gg * 32 + (o2 - 32));
      }
      const float* src = Wf + (size_t)orig * 2048 + c;
      float4 v0 = *(const float4*)src;
      float4 v1 = *(const float4*)(src + 4);
      bf16x8 o8;
      o8[0]=(bf16)v0.x; o8[1]=(bf16)v0.y; o8[2]=(bf16)v0.z; o8[3]=(bf16)v0.w;
      o8[4]=(bf16)v1.x; o8[5]=(bf16)v1.y; o8[6]=(bf16)v1.z; o8[7]=(bf16)v1.w;
      *(bf16x8*)(wfb + e) = o8;
    }
  } else {
    // ---- out zero-init (for gemm2's deterministic atomic K-split reduce) ----
    const long total4 = (long)MROWS * DIMD / 4;
    const long stride = 512L * 256;
    float4 z = {0.f, 0.f, 0.f, 0.f};
    for (long i = (long)(bid - MROWS - 2048) * 256 + t; i < total4; i += stride)
      *(float4*)(out + (i << 2)) = z;
  }
}

// ---------------- GEMM1 (persistent, 1024 blocks x up to 5 tiles):
//                  xn @ Wfp^T, epilogue: fused RoPE (q,k) + SiLU (ff) ----------------
__global__ __launch_bounds__(256, 3) void k_gemm1(const bf16* __restrict__ xn,
                                                  const bf16* __restrict__ wf,
                                                  bf16* __restrict__ q_raw,
                                                  bf16* __restrict__ k_buf,
                                                  bf16* __restrict__ v_t,
                                                  bf16* __restrict__ ffh) {
  __shared__ bf16 As[128*64];
  __shared__ bf16 Bs[128*64];
  const int tid = threadIdx.x, w = tid >> 6, l = tid & 63;
  const int l15 = l & 15, h4 = l >> 4;
  const int wrow = (w >> 1) * 64, nbase = (w & 1) * 64;

  for (int ti = blockIdx.x; ti < G1TILES; ti += 1024) {
    const int bs = (ti & 7) * 584 + (ti >> 3);   // XCD swizzle (4672 = 8*584)
    const int mt = bs & 31, nt = bs >> 5;        // mt-FASTEST: W panel L2-resident per XCD
    const int m0 = mt * 128, f0 = nt * 128;

    f32x4 acc[4][4];
#pragma unroll
    for (int i = 0; i < 4; i++)
#pragma unroll
      for (int j = 0; j < 4; j++) acc[i][j] = (f32x4){0.f,0.f,0.f,0.f};

    auto fa = [&](int t) -> SrcT { return SrcT{ xn + (size_t)m0 * DIMD + t * 64, (long)DIMD }; };
    auto fb = [&](int t) -> SrcT { return SrcT{ wf + (size_t)f0 * DIMD + t * 64, (long)DIMD }; };
    gemm_2ph(fa, fb, DIMD / 64, As, Bs, acc, tid, wrow, nbase, l15, h4);

    if (nt < 16) {
      // pure q region: fused RoPE, scale^power, x1/8
      const int hh = (f0 + nbase) >> 6;
      float invf[2], lsb[2];
#pragma unroll
      for (int nf = 0; nf < 2; nf++) {
        int i = nf*16 + l15;
        invf[nf] = exp2f((float)i * -0.4152410118f);                 // 10000^(-i/32)
        lsb[nf]  = __log2f(((float)(2*i) + 25.6f) * (1.f/89.6f));
      }
#pragma unroll
      for (int m_ = 0; m_ < 4; m_++)
#pragma unroll
        for (int j = 0; j < 4; j++) {
          int m = m0 + wrow + m_*16 + h4*4 + j;
          int n = m & 2047, b = m >> 11;
          float power = ((float)n - 1024.f) * (1.f/512.f);
          bf16* qrow = q_raw + (((size_t)(b*HEADS + hh) * NN + n) << 6);
#pragma unroll
          for (int nf = 0; nf < 2; nf++) {
            float t1 = acc[m_][nf][j], t2 = acc[m_][nf+2][j];
            float sn, cs; __sincosf((float)n * invf[nf], &sn, &cs);
            float sc = exp2f(power * lsb[nf]) * 0.125f;
            int i = nf*16 + l15;
            qrow[i]      = (bf16)((t1*cs - t2*sn) * sc);
            qrow[i + 32] = (bf16)((t2*cs + t1*sn) * sc);
          }
        }
    } else if (nt == 16) {
      if (nbase == 0) {
        // k region: fused RoPE with inverse scale
        float invf[2], lsb[2];
#pragma unroll
        for (int nf = 0; nf < 2; nf++) {
          int i = nf*16 + l15;
          invf[nf] = exp2f((float)i * -0.4152410118f);
          lsb[nf]  = __log2f(((float)(2*i) + 25.6f) * (1.f/89.6f));
        }
#pragma unroll
        for (int m_ = 0; m_ < 4; m_++)
#pragma unroll
          for (int j = 0; j < 4; j++) {
            int m = m0 + wrow + m_*16 + h4*4 + j;
            int n = m & 2047, b = m >> 11;
            float power = ((float)n - 1024.f) * (1.f/512.f);
            bf16* krow = k_buf + (((size_t)(b*NN + n)) << 6);
#pragma unroll
            for (int nf = 0; nf < 2; nf++) {
              float t1 = acc[m_][nf][j], t2 = acc[m_][nf+2][j];
              float sn, cs; __sincosf((float)n * invf[nf], &sn, &cs);
              float sc = exp2f(-power * lsb[nf]);
              int i = nf*16 + l15;
              krow[i]      = (bf16)((t1*cs - t2*sn) * sc);
              krow[i + 32] = (bf16)((t2*cs + t1*sn) * sc);
            }
          }
      } else {
        // v region: plain transposed store
#pragma unroll
        for (int m_ = 0; m_ < 4; m_++)
#pragma unroll
          for (int nf = 0; nf < 4; nf++) {
            int d = nf*16 + l15;
#pragma unroll
            for (int j = 0; j < 4; j++) {
              int m = m0 + wrow + m_*16 + h4*4 + j;
              int n = m & 2047, b = m >> 11;
              v_t[(((size_t)(b*DH + d)) << 11) + n] = (bf16)acc[m_][nf][j];
            }
          }
      }
    } else {
      // ff region (permuted): 64-col group = x[g*32..+32) | gate[g*32..+32)
      int base = f0 + nbase;
      if (base < FUSEDN) {
        int g = (base - 2176) >> 6;
#pragma unroll
        for (int m_ = 0; m_ < 4; m_++)
#pragma unroll
          for (int nf = 0; nf < 2; nf++) {
            int xc = g*32 + nf*16 + l15;
#pragma unroll
            for (int j = 0; j < 4; j++) {
              int m = m0 + wrow + m_*16 + h4*4 + j;
              float xv = acc[m_][nf][j];
              float gv = acc[m_][nf+2][j];
              float sv = gv * (1.f / (1.f + __expf(-gv)));
              ffh[((size_t)m << 13) + xc] = (bf16)(sv * xv);
            }
          }
      }
    }
  }
}

// ---------------- GEMM2 (K-split x2): out += half-K product via atomicAdd ----------------
// out is zeroed by k_prep; exactly two atomic adds per element (one per K-half).
// IEEE fp add is commutative, so the result is bitwise deterministic.
__global__ __launch_bounds__(256, 3) void k_gemm2(const bf16* __restrict__ u_o,
                                                  const bf16* __restrict__ ffh,
                                                  const bf16* __restrict__ wcat,
                                                  float* __restrict__ out) {
  __shared__ bf16 As[128*64];
  __shared__ bf16 Bs[128*64];
  const int tid = threadIdx.x, w = tid >> 6, l = tid & 63;
  const int l15 = l & 15, h4 = l >> 4;
  const int wrow = (w >> 1) * 64, nbase = (w & 1) * 64;
  const int bid = blockIdx.x;
  const int kk = bid >> 9;                        // K-half
  const int inner = bid & 511;
  const int bs = (inner & 7) * 64 + (inner >> 3); // XCD swizzle (512 = 8*64)
  const int mt = bs & 31, nt = bs >> 5;           // mt-FASTEST: Wcat panel L2-resident
  const int m0 = mt * 128, f0 = nt * 128;
  const int T0 = kk * 80;                         // 80 K-steps (K=5120) per half

  f32x4 acc[4][4];
#pragma unroll
  for (int i = 0; i < 4; i++)
#pragma unroll
    for (int j = 0; j < 4; j++) acc[i][j] = (f32x4){0.f,0.f,0.f,0.f};

  auto fa = [&](int t) -> SrcT {
    int tt = t + T0;
    if (tt < 32) return SrcT{ u_o + (size_t)m0 * DIMD + tt * 64, (long)DIMD };
    return SrcT{ ffh + (size_t)m0 * FFI + (tt - 32) * 64, (long)FFI };
  };
  auto fb = [&](int t) -> SrcT { return SrcT{ wcat + (size_t)f0 * K2 + (t + T0) * 64, (long)K2 }; };
  gemm_2ph(fa, fb, 80, As, Bs, acc, tid, wrow, nbase, l15, h4);

#pragma unroll
  for (int m_ = 0; m_ < 4; m_++)
#pragma unroll
    for (int nf = 0; nf < 4; nf++) {
      int fcol = f0 + nbase + nf*16 + l15;
#pragma unroll
      for (int j = 0; j < 4; j++) {
        int m = m0 + wrow + m_*16 + h4*4 + j;
        atomicAdd(out + (size_t)m * DIMD + fcol, acc[m_][nf][j]);
      }
    }
}

// ---------------- fused: causal MQA flash attention (blocks 0-1023, K/V double-buffered)
//                  + Wcat cvt (blocks 1024+) ----------------
__global__ __launch_bounds__(256) void k_attn_cvt(const bf16* __restrict__ qbuf,
                                                  const bf16* __restrict__ kbuf,
                                                  const bf16* __restrict__ vtb,
                                                  bf16* __restrict__ uo,
                                                  const float* __restrict__ Wao,
                                                  const float* __restrict__ Wff,
                                                  bf16* __restrict__ wcat) {
  __shared__ bf16 smem[16384];  // 32 KB total
  const int tid = threadIdx.x, w = tid >> 6, l = tid & 63;
  const int l15 = l & 15, h4 = l >> 4;
  const int bid = blockIdx.x;

  if (bid >= 1024) {
    // ---- Wcat conversion, grid-stride over 1024 blocks ----
    const long stride = 1024L * 256;
    long i0 = (long)(bid - 1024) * 256 + tid;
    for (long i = i0; i < (long)DIMD * DIMD / 8; i += stride) {       // Wao -> wcat[:, :2048]
      long e = i << 3;
      long r = e >> 11; int c = (int)(e & 2047);
      float4 v0 = *(const float4*)(Wao + e);
      float4 v1 = *(const float4*)(Wao + e + 4);
      bf16x8 o;
      o[0]=(bf16)v0.x; o[1]=(bf16)v0.y; o[2]=(bf16)v0.z; o[3]=(bf16)v0.w;
      o[4]=(bf16)v1.x; o[5]=(bf16)v1.y; o[6]=(bf16)v1.z; o[7]=(bf16)v1.w;
      *(bf16x8*)(wcat + r * (long)K2 + c) = o;
    }
    for (long i = i0; i < (long)DIMD * FFI / 8; i += stride) {        // Wff -> wcat[:, 2048:]
      long e = i << 3;
      long r = e >> 13; int c = (int)(e & 8191);
      float4 v0 = *(const float4*)(Wff + e);
      float4 v1 = *(const float4*)(Wff + e + 4);
      bf16x8 o;
      o[0]=(bf16)v0.x; o[1]=(bf16)v0.y; o[2]=(bf16)v0.z; o[3]=(bf16)v0.w;
      o[4]=(bf16)v1.x; o[5]=(bf16)v1.y; o[6]=(bf16)v1.z; o[7]=(bf16)v1.w;
      *(bf16x8*)(wcat + r * (long)K2 + DIMD + c) = o;
    }
    return;
  }

  const int qt = 15 - (bid & 15);     // heavy-first
  const int bh = bid >> 4;
  const int h = bh & (HEADS - 1), b = bh >> 5;
  const int q0 = qt * 128;
  const bf16* Qg = qbuf + ((size_t)(b*HEADS + h) * NN + q0) * DH;
  const bf16* Kg = kbuf + (size_t)b * NN * DH;
  const bf16* Vg = vtb + (size_t)b * DH * NN;

  // ---- Q phase: stage into smem[0,16K), consume to regs ----
#pragma unroll
  for (int c = 0; c < 4; c++) {
    int chunk = c*256 + tid;
    int r = chunk >> 3, cc = chunk & 7;
    int col8 = (cc ^ (r & 7)) << 3;
    gl_lds16(Qg + (size_t)r*DH + col8, smem + ((size_t)(chunk & ~63) << 3));
  }
  __syncthreads();

  const int wq0 = q0 + w*32;
  bf16x8 qfr[2][2];
#pragma unroll
  for (int qf = 0; qf < 2; qf++)
#pragma unroll
    for (int c = 0; c < 2; c++) {
      int row = w*32 + qf*16 + l15;
      int x = (64*c + 16*h4) ^ (16*(row & 7));
      qfr[qf][c] = *(const bf16x8*)((const char*)smem + row*128 + x);
    }
  __syncthreads();   // all Q reads done; vm/lgkm ledger = 0; smem free

  // ---- K/V double-buffer setup ----
  bf16 *curK = smem,        *nxtK = smem + 4096;
  bf16 *curV = smem + 8192, *nxtV = smem + 12288;

  f32x4 zf = {0.f,0.f,0.f,0.f};
  f32x4 o_[2][4];
#pragma unroll
  for (int qf = 0; qf < 2; qf++)
#pragma unroll
    for (int nf = 0; nf < 4; nf++) o_[qf][nf] = zf;
  float mrun[2] = {-3e38f, -3e38f};
  float lrun[2] = {0.f, 0.f};

  const int nsteps = (q0 + 128) >> 6;
  stage_i<256>(Kg, DH, curK, 0, tid);
  stage_i<256>(Kg, DH, curK, 1, tid);
  stage_i<256>(Vg, NN, curV, 0, tid);
  stage_i<256>(Vg, NN, curV, 1, tid);

  for (int kt = 0; kt < nsteps; kt++) {
    const int kv0 = kt << 6;
    if (kt + 1 < nsteps) {
      const int kv1 = kv0 + 64;
      stage_i<256>(Kg + (size_t)kv1 * DH, DH, nxtK, 0, tid);
      stage_i<256>(Kg + (size_t)kv1 * DH, DH, nxtK, 1, tid);
      stage_i<256>(Vg + kv1, NN, nxtV, 0, tid);
      stage_i<256>(Vg + kv1, NN, nxtV, 1, tid);
      asm volatile("s_waitcnt vmcnt(4)" ::: "memory");  // drain tile kt only
    } else {
      asm volatile("s_waitcnt vmcnt(0)" ::: "memory");
    }
    __builtin_amdgcn_s_barrier();        // tile kt ready in cur
    if (kv0 <= wq0 + 31) {
      bf16x8 ka[4][2];
#pragma unroll
      for (int kvf = 0; kvf < 4; kvf++)
#pragma unroll
        for (int c = 0; c < 2; c++) {
          int r = kvf*16 + l15;
          int x = (64*c + 16*h4) ^ (16*(r & 7));
          ka[kvf][c] = *(const bf16x8*)((const char*)curK + r*128 + x);
        }
      f32x4 st[4][2];
#pragma unroll
      for (int kvf = 0; kvf < 4; kvf++)
#pragma unroll
        for (int qf = 0; qf < 2; qf++) {
          f32x4 s = __builtin_amdgcn_mfma_f32_16x16x32_bf16(ka[kvf][0], qfr[qf][0], zf, 0, 0, 0);
          s = __builtin_amdgcn_mfma_f32_16x16x32_bf16(ka[kvf][1], qfr[qf][1], s, 0, 0, 0);
          st[kvf][qf] = s;
        }
      if (kv0 + 63 > wq0) {
#pragma unroll
        for (int kvf = 0; kvf < 4; kvf++)
#pragma unroll
          for (int j = 0; j < 4; j++) {
            int kvg = kv0 + kvf*16 + h4*4 + j;
#pragma unroll
            for (int qf = 0; qf < 2; qf++) {
              int qg = wq0 + qf*16 + l15;
              if (kvg > qg) st[kvf][qf][j] = -3e38f;
            }
          }
      }
      bf16x8 pa[2][2];
#pragma unroll
      for (int qf = 0; qf < 2; qf++) {
        float vmax = -3e38f;
#pragma unroll
        for (int kvf = 0; kvf < 4; kvf++)
#pragma unroll
          for (int j = 0; j < 4; j++) vmax = fmaxf(vmax, st[kvf][qf][j]);
        vmax = fmaxf(vmax, __shfl_xor(vmax, 16));
        vmax = fmaxf(vmax, __shfl_xor(vmax, 32));
        float mnew = fmaxf(mrun[qf], vmax);
        float corr = __expf(mrun[qf] - mnew);
        float ps = 0.f;
        float pv_[16];
#pragma unroll
        for (int kvf = 0; kvf < 4; kvf++)
#pragma unroll
          for (int j = 0; j < 4; j++) {
            float p = __expf(st[kvf][qf][j] - mnew);
            pv_[kvf*4 + j] = p; ps += p;
          }
        ps += __shfl_xor(ps, 16);
        ps += __shfl_xor(ps, 32);
        lrun[qf] = lrun[qf]*corr + ps;
        mrun[qf] = mnew;
        bf16x8 t0, t1;
#pragma unroll
        for (int i = 0; i < 8; i++) { t0[i] = (bf16)pv_[i]; t1[i] = (bf16)pv_[8+i]; }
        pa[qf][0] = t0; pa[qf][1] = t1;
#pragma unroll
        for (int j = 0; j < 4; j++) {
          float cj = __shfl(corr, (l & 48) | (h4*4 + j), 64);
#pragma unroll
          for (int nf = 0; nf < 4; nf++) o_[qf][nf][j] *= cj;
        }
      }
#pragma unroll
      for (int nf = 0; nf < 4; nf++) {
        int d_ = nf*16 + l15;
        int swz = 16*(d_ & 7);
        const char* vrow = (const char*)curV + d_*128;
#pragma unroll
        for (int hc = 0; hc < 2; hc++) {
          bf16x4 v0 = *(const bf16x4*)(vrow + ((hc*64 + 8*h4) ^ swz));
          bf16x4 v1 = *(const bf16x4*)(vrow + ((hc*64 + 32 + 8*h4) ^ swz));
          bf16x8 vb = __builtin_shufflevector(v0, v1, 0,1,2,3,4,5,6,7);
#pragma unroll
          for (int qf = 0; qf < 2; qf++)
            o_[qf][nf] = __builtin_amdgcn_mfma_f32_16x16x32_bf16(pa[qf][hc], vb, o_[qf][nf], 0, 0, 0);
        }
      }
    }
    __builtin_amdgcn_s_barrier();        // all reads of cur done -> may overwrite next iter
    { bf16* t_ = curK; curK = nxtK; nxtK = t_; }
    { bf16* t_ = curV; curV = nxtV; nxtV = t_; }
  }
#pragma unroll
  for (int qf = 0; qf < 2; qf++) {
    float inv = 1.f / lrun[qf];
#pragma unroll
    for (int j = 0; j < 4; j++) {
      float ij = __shfl(inv, (l & 48) | (h4*4 + j), 64);
      int qg = wq0 + qf*16 + h4*4 + j;
      size_t rowoff = (size_t)(b*NN + qg) * DIMD + h*DH;
#pragma unroll
      for (int nf = 0; nf < 4; nf++)
        uo[rowoff + nf*16 + l15] = (bf16)(o_[qf][nf][j] * ij);
    }
  }
}

extern "C" void kernel_launch(void* const* d_in, const int* in_sizes, int n_in,
                              void* d_out, int out_size, void* d_ws, size_t ws_size,
                              hipStream_t stream) {
  const float* x     = (const float*)d_in[0];
  const float* gamma = (const float*)d_in[1];
  const float* Wf    = (const float*)d_in[2];
  const float* Wao   = (const float*)d_in[3];
  const float* Wff   = (const float*)d_in[4];
  float* out = (float*)d_out;
  char* ws = (char*)d_ws;

  size_t o = 0;
  bf16* wfb     = (bf16*)(ws + o); o += (size_t)FUSEDP * DIMD * 2;   // padded, permuted
  bf16* wcat    = wfb;                                               // aliased after GEMM1
  bf16* xn      = (bf16*)(ws + o); o += (size_t)MROWS * DIMD * 2;
  bf16* q_raw   = (bf16*)(ws + o); o += (size_t)BB*HEADS*NN*DH * 2;
  bf16* k_buf   = (bf16*)(ws + o); o += (size_t)BB*NN*DH * 2;
  bf16* v_t     = (bf16*)(ws + o); o += (size_t)BB*DH*NN * 2;
  bf16* ffh     = (bf16*)(ws + o); o += (size_t)MROWS * FFI * 2;     // compact gated ff
  bf16* u_o     = (bf16*)(ws + o); o += (size_t)MROWS * DIMD * 2;

  k_prep<<<MROWS + 2048 + 512, 256, 0, stream>>>(x, gamma, xn, Wf, wfb, out);
  k_gemm1<<<1024, 256, 0, stream>>>(xn, wfb, q_raw, k_buf, v_t, ffh);
  k_attn_cvt<<<2048, 256, 0, stream>>>(q_raw, k_buf, v_t, u_o, Wao, Wff, wcat);
  k_gemm2<<<2*(MROWS/128)*(DIMD/128), 256, 0, stream>>>(u_o, ffh, wcat, out);
}

// Round 15
// 715.591 us; speedup vs baseline: 1.0389x; 1.0389x over previous
//
#include <hip/hip_runtime.h>
#include <cstdint>
#include <cstddef>

typedef __bf16 bf16;
typedef float f32x4 __attribute__((ext_vector_type(4)));
typedef bf16  bf16x4 __attribute__((ext_vector_type(4)));
typedef bf16  bf16x8 __attribute__((ext_vector_type(8)));

#define DIMD   2048
#define HEADS  32
#define DH     64
#define FFI    8192
#define FUSEDN 18560
#define FUSEDP 18688   // padded to 146*128
#define BB     2
#define NN     2048
#define MROWS  4096   // BB*NN
#define K2     10240  // DIMD + FFI
#define G1TILES 4672  // (FUSEDP/128)*(MROWS/128)

// async global->LDS, 16B per lane, wave-uniform LDS base
__device__ __forceinline__ void gl_lds16(const void* g, void* l) {
  __builtin_amdgcn_global_load_lds(
      (__attribute__((address_space(1))) void*)const_cast<void*>(g),
      (__attribute__((address_space(3))) void*)l, 16, 0, 0);
}

// Stage one gl_lds instruction of a [rows][64] bf16 tile into LDS.
// LDS dest linear (gl_lds constraint); T2 swizzle applied on the GLOBAL
// source: LDS chunk (row, c) receives global chunk (row, c^(row&7)).
template <int THREADS>
__device__ __forceinline__ void stage_i(const bf16* g, long ldk,
                                        bf16* region, int instr, int tid) {
  int row = instr * (THREADS / 8) + (tid >> 3);
  int cs  = (tid & 7) ^ (row & 7);
  gl_lds16(g + (size_t)row * ldk + cs * 8,
           region + (size_t)instr * (THREADS * 8) + (size_t)(tid & ~63) * 8);
}

struct SrcT { const bf16* g; long ldk; };

// ---- m97-style 2-barrier GEMM core: 128x128 tile, BK=64, 256 thr, 32KB LDS ----
template <typename FA, typename FB>
__device__ __forceinline__ void gemm_2ph(FA fa, FB fb, const int NT,
    bf16* As, bf16* Bs, f32x4 (&acc)[4][4],
    const int tid, const int wrow, const int nbase, const int l15, const int h4)
{
  const char* aP[2]; const char* bP[2];
  const int arow = wrow + l15, brow = nbase + l15;
#pragma unroll
  for (int ks = 0; ks < 2; ks++) {
    aP[ks] = (const char*)As + arow * 128 + (((ks * 4 + h4) ^ (arow & 7)) * 16);
    bP[ks] = (const char*)Bs + brow * 128 + (((ks * 4 + h4) ^ (brow & 7)) * 16);
  }
  for (int t = 0; t < NT; ++t) {
    __syncthreads();                       // WAR: all reads of tile t-1 done
    {
      auto a = fa(t); auto b = fb(t);
#pragma unroll
      for (int q = 0; q < 4; q++) stage_i<256>(a.g, a.ldk, As, q, tid);
#pragma unroll
      for (int q = 0; q < 4; q++) stage_i<256>(b.g, b.ldk, Bs, q, tid);
    }
    __syncthreads();                       // full drain: tile t ready
#pragma unroll
    for (int ks = 0; ks < 2; ks++) {
      bf16x8 af[4], bfr[4];
#pragma unroll
      for (int m_ = 0; m_ < 4; m_++) af[m_]  = *(const bf16x8*)(aP[ks] + m_ * 2048);
#pragma unroll
      for (int n_ = 0; n_ < 4; n_++) bfr[n_] = *(const bf16x8*)(bP[ks] + n_ * 2048);
#pragma unroll
      for (int m_ = 0; m_ < 4; m_++)
#pragma unroll
        for (int n_ = 0; n_ < 4; n_++)
          acc[m_][n_] = __builtin_amdgcn_mfma_f32_16x16x32_bf16(af[m_], bfr[n_], acc[m_][n_], 0, 0, 0);
    }
  }
}

// ---------------- fused prep: LN rows (bid<MROWS) + Wf permuted cvt (rest) ----------------
__global__ __launch_bounds__(256) void k_prep(const float* __restrict__ x,
                                              const float* __restrict__ g,
                                              bf16* __restrict__ xn,
                                              const float* __restrict__ Wf,
                                              bf16* __restrict__ wfb) {
  __shared__ float rs[8];
  const int bid = blockIdx.x, t = threadIdx.x;
  if (bid < MROWS) {
    // ---- LayerNorm row ----
    int row = bid;
    const float4* xr = (const float4*)(x + (size_t)row * DIMD);
    float4 a = xr[t*2], b = xr[t*2+1];
    float s  = a.x+a.y+a.z+a.w + b.x+b.y+b.z+b.w;
    float s2 = a.x*a.x+a.y*a.y+a.z*a.z+a.w*a.w + b.x*b.x+b.y*b.y+b.z*b.z+b.w*b.w;
    for (int o = 1; o < 64; o <<= 1) { s += __shfl_xor(s, o); s2 += __shfl_xor(s2, o); }
    if ((t & 63) == 0) { rs[t>>6] = s; rs[4 + (t>>6)] = s2; }
    __syncthreads();
    s = rs[0]+rs[1]+rs[2]+rs[3]; s2 = rs[4]+rs[5]+rs[6]+rs[7];
    float mu = s * (1.f/DIMD);
    float var = s2 * (1.f/DIMD) - mu*mu;
    float rstd = rsqrtf(var + 1e-5f);
    const float4* gr = (const float4*)g;
    float4 g0 = gr[t*2], g1 = gr[t*2+1];
    bf16x8 o;
    o[0]=(bf16)((a.x-mu)*rstd*g0.x); o[1]=(bf16)((a.y-mu)*rstd*g0.y);
    o[2]=(bf16)((a.z-mu)*rstd*g0.z); o[3]=(bf16)((a.w-mu)*rstd*g0.w);
    o[4]=(bf16)((b.x-mu)*rstd*g1.x); o[5]=(bf16)((b.y-mu)*rstd*g1.y);
    o[6]=(bf16)((b.z-mu)*rstd*g1.z); o[7]=(bf16)((b.w-mu)*rstd*g1.w);
    *(bf16x8*)(xn + (size_t)row * DIMD + t*8) = o;
  } else {
    // ---- Wf -> wfb with ff x/gate interleave permutation (grid-stride) ----
    const long total8 = (long)FUSEDN * DIMD / 8;
    const long stride = 2048L * 256;
    for (long i = (long)(bid - MROWS) * 256 + t; i < total8; i += stride) {
      long e = i << 3;
      int p = (int)(e >> 11);
      int c = (int)(e & 2047);
      int orig;
      if (p < 2176) orig = p;
      else {
        int q = p - 2176, gg = q >> 6, o2 = q & 63;
        orig = (o2 < 32) ? (2176 + gg * 32 + o2) : (2176 + 8192 + gg * 32 + (o2 - 32));
      }
      const float* src = Wf + (size_t)orig * 2048 + c;
      float4 v0 = *(const float4*)src;
      float4 v1 = *(const float4*)(src + 4);
      bf16x8 o8;
      o8[0]=(bf16)v0.x; o8[1]=(bf16)v0.y; o8[2]=(bf16)v0.z; o8[3]=(bf16)v0.w;
      o8[4]=(bf16)v1.x; o8[5]=(bf16)v1.y; o8[6]=(bf16)v1.z; o8[7]=(bf16)v1.w;
      *(bf16x8*)(wfb + e) = o8;
    }
  }
}

// ---------------- GEMM1 (persistent, 1024 blocks x up to 5 tiles):
//                  xn @ Wfp^T, epilogue: fused RoPE (q,k) + SiLU (ff) ----------------
__global__ __launch_bounds__(256, 3) void k_gemm1(const bf16* __restrict__ xn,
                                                  const bf16* __restrict__ wf,
                                                  bf16* __restrict__ q_raw,
                                                  bf16* __restrict__ k_buf,
                                                  bf16* __restrict__ v_t,
                                                  bf16* __restrict__ ffh) {
  __shared__ bf16 As[128*64];
  __shared__ bf16 Bs[128*64];
  const int tid = threadIdx.x, w = tid >> 6, l = tid & 63;
  const int l15 = l & 15, h4 = l >> 4;
  const int wrow = (w >> 1) * 64, nbase = (w & 1) * 64;

  for (int ti = blockIdx.x; ti < G1TILES; ti += 1024) {
    const int bs = (ti & 7) * 584 + (ti >> 3);   // XCD swizzle (4672 = 8*584)
    const int mt = bs & 31, nt = bs >> 5;        // mt-FASTEST: W panel L2-resident per XCD
    const int m0 = mt * 128, f0 = nt * 128;

    f32x4 acc[4][4];
#pragma unroll
    for (int i = 0; i < 4; i++)
#pragma unroll
      for (int j = 0; j < 4; j++) acc[i][j] = (f32x4){0.f,0.f,0.f,0.f};

    auto fa = [&](int t) -> SrcT { return SrcT{ xn + (size_t)m0 * DIMD + t * 64, (long)DIMD }; };
    auto fb = [&](int t) -> SrcT { return SrcT{ wf + (size_t)f0 * DIMD + t * 64, (long)DIMD }; };
    gemm_2ph(fa, fb, DIMD / 64, As, Bs, acc, tid, wrow, nbase, l15, h4);

    if (nt < 16) {
      // pure q region: fused RoPE, scale^power, x1/8
      const int hh = (f0 + nbase) >> 6;
      float invf[2], lsb[2];
#pragma unroll
      for (int nf = 0; nf < 2; nf++) {
        int i = nf*16 + l15;
        invf[nf] = exp2f((float)i * -0.4152410118f);                 // 10000^(-i/32)
        lsb[nf]  = __log2f(((float)(2*i) + 25.6f) * (1.f/89.6f));
      }
#pragma unroll
      for (int m_ = 0; m_ < 4; m_++)
#pragma unroll
        for (int j = 0; j < 4; j++) {
          int m = m0 + wrow + m_*16 + h4*4 + j;
          int n = m & 2047, b = m >> 11;
          float power = ((float)n - 1024.f) * (1.f/512.f);
          bf16* qrow = q_raw + (((size_t)(b*HEADS + hh) * NN + n) << 6);
#pragma unroll
          for (int nf = 0; nf < 2; nf++) {
            float t1 = acc[m_][nf][j], t2 = acc[m_][nf+2][j];
            float sn, cs; __sincosf((float)n * invf[nf], &sn, &cs);
            float sc = exp2f(power * lsb[nf]) * 0.125f;
            int i = nf*16 + l15;
            qrow[i]      = (bf16)((t1*cs - t2*sn) * sc);
            qrow[i + 32] = (bf16)((t2*cs + t1*sn) * sc);
          }
        }
    } else if (nt == 16) {
      if (nbase == 0) {
        // k region: fused RoPE with inverse scale
        float invf[2], lsb[2];
#pragma unroll
        for (int nf = 0; nf < 2; nf++) {
          int i = nf*16 + l15;
          invf[nf] = exp2f((float)i * -0.4152410118f);
          lsb[nf]  = __log2f(((float)(2*i) + 25.6f) * (1.f/89.6f));
        }
#pragma unroll
        for (int m_ = 0; m_ < 4; m_++)
#pragma unroll
          for (int j = 0; j < 4; j++) {
            int m = m0 + wrow + m_*16 + h4*4 + j;
            int n = m & 2047, b = m >> 11;
            float power = ((float)n - 1024.f) * (1.f/512.f);
            bf16* krow = k_buf + (((size_t)(b*NN + n)) << 6);
#pragma unroll
            for (int nf = 0; nf < 2; nf++) {
              float t1 = acc[m_][nf][j], t2 = acc[m_][nf+2][j];
              float sn, cs; __sincosf((float)n * invf[nf], &sn, &cs);
              float sc = exp2f(-power * lsb[nf]);
              int i = nf*16 + l15;
              krow[i]      = (bf16)((t1*cs - t2*sn) * sc);
              krow[i + 32] = (bf16)((t2*cs + t1*sn) * sc);
            }
          }
      } else {
        // v region: plain transposed store
#pragma unroll
        for (int m_ = 0; m_ < 4; m_++)
#pragma unroll
          for (int nf = 0; nf < 4; nf++) {
            int d = nf*16 + l15;
#pragma unroll
            for (int j = 0; j < 4; j++) {
              int m = m0 + wrow + m_*16 + h4*4 + j;
              int n = m & 2047, b = m >> 11;
              v_t[(((size_t)(b*DH + d)) << 11) + n] = (bf16)acc[m_][nf][j];
            }
          }
      }
    } else {
      // ff region (permuted): 64-col group = x[g*32..+32) | gate[g*32..+32)
      int base = f0 + nbase;
      if (base < FUSEDN) {
        int g = (base - 2176) >> 6;
#pragma unroll
        for (int m_ = 0; m_ < 4; m_++)
#pragma unroll
          for (int nf = 0; nf < 2; nf++) {
            int xc = g*32 + nf*16 + l15;
#pragma unroll
            for (int j = 0; j < 4; j++) {
              int m = m0 + wrow + m_*16 + h4*4 + j;
              float xv = acc[m_][nf][j];
              float gv = acc[m_][nf+2][j];
              float sv = gv * (1.f / (1.f + __expf(-gv)));
              ffh[((size_t)m << 13) + xc] = (bf16)(sv * xv);
            }
          }
      }
    }
  }
}

// ---------------- GEMM2 (K-split x2): out/part = [O | ffh] @ Wcat^T -> fp32 ----------------
__global__ __launch_bounds__(256, 3) void k_gemm2(const bf16* __restrict__ u_o,
                                                  const bf16* __restrict__ ffh,
                                                  const bf16* __restrict__ wcat,
                                                  float* __restrict__ out,
                                                  float* __restrict__ part) {
  __shared__ bf16 As[128*64];
  __shared__ bf16 Bs[128*64];
  const int tid = threadIdx.x, w = tid >> 6, l = tid & 63;
  const int l15 = l & 15, h4 = l >> 4;
  const int wrow = (w >> 1) * 64, nbase = (w & 1) * 64;
  const int bid = blockIdx.x;
  const int kk = bid >> 9;                        // K-half: 0 -> out, 1 -> part
  const int inner = bid & 511;
  const int bs = (inner & 7) * 64 + (inner >> 3); // XCD swizzle (512 = 8*64)
  const int mt = bs & 31, nt = bs >> 5;           // mt-FASTEST: Wcat panel L2-resident
  const int m0 = mt * 128, f0 = nt * 128;
  const int T0 = kk * 80;                         // 80 K-steps (K=5120) per half

  f32x4 acc[4][4];
#pragma unroll
  for (int i = 0; i < 4; i++)
#pragma unroll
    for (int j = 0; j < 4; j++) acc[i][j] = (f32x4){0.f,0.f,0.f,0.f};

  auto fa = [&](int t) -> SrcT {
    int tt = t + T0;
    if (tt < 32) return SrcT{ u_o + (size_t)m0 * DIMD + tt * 64, (long)DIMD };
    return SrcT{ ffh + (size_t)m0 * FFI + (tt - 32) * 64, (long)FFI };
  };
  auto fb = [&](int t) -> SrcT { return SrcT{ wcat + (size_t)f0 * K2 + (t + T0) * 64, (long)K2 }; };
  gemm_2ph(fa, fb, 80, As, Bs, acc, tid, wrow, nbase, l15, h4);

  float* dst = kk ? part : out;
#pragma unroll
  for (int m_ = 0; m_ < 4; m_++)
#pragma unroll
    for (int nf = 0; nf < 4; nf++) {
      int fcol = f0 + nbase + nf*16 + l15;
#pragma unroll
      for (int j = 0; j < 4; j++) {
        int m = m0 + wrow + m_*16 + h4*4 + j;
        dst[(size_t)m * DIMD + fcol] = acc[m_][nf][j];
      }
    }
}

// ---------------- out += part (deterministic K-split reduce) ----------------
__global__ void k_addout(float* __restrict__ out, const float* __restrict__ part, long total4) {
  long stride = (long)gridDim.x * blockDim.x;
  for (long i = (long)blockIdx.x * blockDim.x + threadIdx.x; i < total4; i += stride) {
    long e = i << 2;
    float4 a = *(const float4*)(out + e);
    float4 b = *(const float4*)(part + e);
    float4 r; r.x = a.x + b.x; r.y = a.y + b.y; r.z = a.z + b.z; r.w = a.w + b.w;
    *(float4*)(out + e) = r;
  }
}

// ---------------- fused: causal MQA flash attention (blocks 0-1023, K/V double-buffered)
//                  + Wcat cvt (blocks 1024+) ----------------
__global__ __launch_bounds__(256) void k_attn_cvt(const bf16* __restrict__ qbuf,
                                                  const bf16* __restrict__ kbuf,
                                                  const bf16* __restrict__ vtb,
                                                  bf16* __restrict__ uo,
                                                  const float* __restrict__ Wao,
                                                  const float* __restrict__ Wff,
                                                  bf16* __restrict__ wcat) {
  __shared__ bf16 smem[16384];  // 32 KB total
  const int tid = threadIdx.x, w = tid >> 6, l = tid & 63;
  const int l15 = l & 15, h4 = l >> 4;
  const int bid = blockIdx.x;

  if (bid >= 1024) {
    // ---- Wcat conversion, grid-stride over 1024 blocks ----
    const long stride = 1024L * 256;
    long i0 = (long)(bid - 1024) * 256 + tid;
    for (long i = i0; i < (long)DIMD * DIMD / 8; i += stride) {       // Wao -> wcat[:, :2048]
      long e = i << 3;
      long r = e >> 11; int c = (int)(e & 2047);
      float4 v0 = *(const float4*)(Wao + e);
      float4 v1 = *(const float4*)(Wao + e + 4);
      bf16x8 o;
      o[0]=(bf16)v0.x; o[1]=(bf16)v0.y; o[2]=(bf16)v0.z; o[3]=(bf16)v0.w;
      o[4]=(bf16)v1.x; o[5]=(bf16)v1.y; o[6]=(bf16)v1.z; o[7]=(bf16)v1.w;
      *(bf16x8*)(wcat + r * (long)K2 + c) = o;
    }
    for (long i = i0; i < (long)DIMD * FFI / 8; i += stride) {        // Wff -> wcat[:, 2048:]
      long e = i << 3;
      long r = e >> 13; int c = (int)(e & 8191);
      float4 v0 = *(const float4*)(Wff + e);
      float4 v1 = *(const float4*)(Wff + e + 4);
      bf16x8 o;
      o[0]=(bf16)v0.x; o[1]=(bf16)v0.y; o[2]=(bf16)v0.z; o[3]=(bf16)v0.w;
      o[4]=(bf16)v1.x; o[5]=(bf16)v1.y; o[6]=(bf16)v1.z; o[7]=(bf16)v1.w;
      *(bf16x8*)(wcat + r * (long)K2 + DIMD + c) = o;
    }
    return;
  }

  const int qt = 15 - (bid & 15);     // heavy-first
  const int bh = bid >> 4;
  const int h = bh & (HEADS - 1), b = bh >> 5;
  const int q0 = qt * 128;
  const bf16* Qg = qbuf + ((size_t)(b*HEADS + h) * NN + q0) * DH;
  const bf16* Kg = kbuf + (size_t)b * NN * DH;
  const bf16* Vg = vtb + (size_t)b * DH * NN;

  // ---- Q phase: stage into smem[0,16K), consume to regs ----
#pragma unroll
  for (int c = 0; c < 4; c++) {
    int chunk = c*256 + tid;
    int r = chunk >> 3, cc = chunk & 7;
    int col8 = (cc ^ (r & 7)) << 3;
    gl_lds16(Qg + (size_t)r*DH + col8, smem + ((size_t)(chunk & ~63) << 3));
  }
  __syncthreads();

  const int wq0 = q0 + w*32;
  bf16x8 qfr[2][2];
#pragma unroll
  for (int qf = 0; qf < 2; qf++)
#pragma unroll
    for (int c = 0; c < 2; c++) {
      int row = w*32 + qf*16 + l15;
      int x = (64*c + 16*h4) ^ (16*(row & 7));
      qfr[qf][c] = *(const bf16x8*)((const char*)smem + row*128 + x);
    }
  __syncthreads();   // all Q reads done; vm/lgkm ledger = 0; smem free

  // ---- K/V double-buffer setup ----
  bf16 *curK = smem,        *nxtK = smem + 4096;
  bf16 *curV = smem + 8192, *nxtV = smem + 12288;

  f32x4 zf = {0.f,0.f,0.f,0.f};
  f32x4 o_[2][4];
#pragma unroll
  for (int qf = 0; qf < 2; qf++)
#pragma unroll
    for (int nf = 0; nf < 4; nf++) o_[qf][nf] = zf;
  float mrun[2] = {-3e38f, -3e38f};
  float lrun[2] = {0.f, 0.f};

  const int nsteps = (q0 + 128) >> 6;
  stage_i<256>(Kg, DH, curK, 0, tid);
  stage_i<256>(Kg, DH, curK, 1, tid);
  stage_i<256>(Vg, NN, curV, 0, tid);
  stage_i<256>(Vg, NN, curV, 1, tid);

  for (int kt = 0; kt < nsteps; kt++) {
    const int kv0 = kt << 6;
    if (kt + 1 < nsteps) {
      const int kv1 = kv0 + 64;
      stage_i<256>(Kg + (size_t)kv1 * DH, DH, nxtK, 0, tid);
      stage_i<256>(Kg + (size_t)kv1 * DH, DH, nxtK, 1, tid);
      stage_i<256>(Vg + kv1, NN, nxtV, 0, tid);
      stage_i<256>(Vg + kv1, NN, nxtV, 1, tid);
      asm volatile("s_waitcnt vmcnt(4)" ::: "memory");  // drain tile kt only
    } else {
      asm volatile("s_waitcnt vmcnt(0)" ::: "memory");
    }
    __builtin_amdgcn_s_barrier();        // tile kt ready in cur
    if (kv0 <= wq0 + 31) {
      bf16x8 ka[4][2];
#pragma unroll
      for (int kvf = 0; kvf < 4; kvf++)
#pragma unroll
        for (int c = 0; c < 2; c++) {
          int r = kvf*16 + l15;
          int x = (64*c + 16*h4) ^ (16*(r & 7));
          ka[kvf][c] = *(const bf16x8*)((const char*)curK + r*128 + x);
        }
      f32x4 st[4][2];
#pragma unroll
      for (int kvf = 0; kvf < 4; kvf++)
#pragma unroll
        for (int qf = 0; qf < 2; qf++) {
          f32x4 s = __builtin_amdgcn_mfma_f32_16x16x32_bf16(ka[kvf][0], qfr[qf][0], zf, 0, 0, 0);
          s = __builtin_amdgcn_mfma_f32_16x16x32_bf16(ka[kvf][1], qfr[qf][1], s, 0, 0, 0);
          st[kvf][qf] = s;
        }
      if (kv0 + 63 > wq0) {
#pragma unroll
        for (int kvf = 0; kvf < 4; kvf++)
#pragma unroll
          for (int j = 0; j < 4; j++) {
            int kvg = kv0 + kvf*16 + h4*4 + j;
#pragma unroll
            for (int qf = 0; qf < 2; qf++) {
              int qg = wq0 + qf*16 + l15;
              if (kvg > qg) st[kvf][qf][j] = -3e38f;
            }
          }
      }
      bf16x8 pa[2][2];
#pragma unroll
      for (int qf = 0; qf < 2; qf++) {
        float vmax = -3e38f;
#pragma unroll
        for (int kvf = 0; kvf < 4; kvf++)
#pragma unroll
          for (int j = 0; j < 4; j++) vmax = fmaxf(vmax, st[kvf][qf][j]);
        vmax = fmaxf(vmax, __shfl_xor(vmax, 16));
        vmax = fmaxf(vmax, __shfl_xor(vmax, 32));
        float mnew = fmaxf(mrun[qf], vmax);
        float corr = __expf(mrun[qf] - mnew);
        float ps = 0.f;
        float pv_[16];
#pragma unroll
        for (int kvf = 0; kvf < 4; kvf++)
#pragma unroll
          for (int j = 0; j < 4; j++) {
            float p = __expf(st[kvf][qf][j] - mnew);
            pv_[kvf*4 + j] = p; ps += p;
          }
        ps += __shfl_xor(ps, 16);
        ps += __shfl_xor(ps, 32);
        lrun[qf] = lrun[qf]*corr + ps;
        mrun[qf] = mnew;
        bf16x8 t0, t1;
#pragma unroll
        for (int i = 0; i < 8; i++) { t0[i] = (bf16)pv_[i]; t1[i] = (bf16)pv_[8+i]; }
        pa[qf][0] = t0; pa[qf][1] = t1;
#pragma unroll
        for (int j = 0; j < 4; j++) {
          float cj = __shfl(corr, (l & 48) | (h4*4 + j), 64);
#pragma unroll
          for (int nf = 0; nf < 4; nf++) o_[qf][nf][j] *= cj;
        }
      }
#pragma unroll
      for (int nf = 0; nf < 4; nf++) {
        int d_ = nf*16 + l15;
        int swz = 16*(d_ & 7);
        const char* vrow = (const char*)curV + d_*128;
#pragma unroll
        for (int hc = 0; hc < 2; hc++) {
          bf16x4 v0 = *(const bf16x4*)(vrow + ((hc*64 + 8*h4) ^ swz));
          bf16x4 v1 = *(const bf16x4*)(vrow + ((hc*64 + 32 + 8*h4) ^ swz));
          bf16x8 vb = __builtin_shufflevector(v0, v1, 0,1,2,3,4,5,6,7);
#pragma unroll
          for (int qf = 0; qf < 2; qf++)
            o_[qf][nf] = __builtin_amdgcn_mfma_f32_16x16x32_bf16(pa[qf][hc], vb, o_[qf][nf], 0, 0, 0);
        }
      }
    }
    __builtin_amdgcn_s_barrier();        // all reads of cur done -> may overwrite next iter
    { bf16* t_ = curK; curK = nxtK; nxtK = t_; }
    { bf16* t_ = curV; curV = nxtV; nxtV = t_; }
  }
#pragma unroll
  for (int qf = 0; qf < 2; qf++) {
    float inv = 1.f / lrun[qf];
#pragma unroll
    for (int j = 0; j < 4; j++) {
      float ij = __shfl(inv, (l & 48) | (h4*4 + j), 64);
      int qg = wq0 + qf*16 + h4*4 + j;
      size_t rowoff = (size_t)(b*NN + qg) * DIMD + h*DH;
#pragma unroll
      for (int nf = 0; nf < 4; nf++)
        uo[rowoff + nf*16 + l15] = (bf16)(o_[qf][nf][j] * ij);
    }
  }
}

extern "C" void kernel_launch(void* const* d_in, const int* in_sizes, int n_in,
                              void* d_out, int out_size, void* d_ws, size_t ws_size,
                              hipStream_t stream) {
  const float* x     = (const float*)d_in[0];
  const float* gamma = (const float*)d_in[1];
  const float* Wf    = (const float*)d_in[2];
  const float* Wao   = (const float*)d_in[3];
  const float* Wff   = (const float*)d_in[4];
  float* out = (float*)d_out;
  char* ws = (char*)d_ws;

  size_t o = 0;
  bf16* wfb     = (bf16*)(ws + o); o += (size_t)FUSEDP * DIMD * 2;   // padded, permuted
  bf16* wcat    = wfb;                                               // aliased after GEMM1
  bf16* xn      = (bf16*)(ws + o); o += (size_t)MROWS * DIMD * 2;
  bf16* q_raw   = (bf16*)(ws + o); o += (size_t)BB*HEADS*NN*DH * 2;
  bf16* k_buf   = (bf16*)(ws + o); o += (size_t)BB*NN*DH * 2;
  bf16* v_t     = (bf16*)(ws + o); o += (size_t)BB*DH*NN * 2;
  bf16* ffh     = (bf16*)(ws + o); o += (size_t)MROWS * FFI * 2;     // compact gated ff
  bf16* u_o     = (bf16*)(ws + o); o += (size_t)MROWS * DIMD * 2;
  // fp32 K-split partial aliased over xn+q_raw (both dead by gemm2)
  float* part   = (float*)xn;

  k_prep<<<MROWS + 2048, 256, 0, stream>>>(x, gamma, xn, Wf, wfb);
  k_gemm1<<<1024, 256, 0, stream>>>(xn, wfb, q_raw, k_buf, v_t, ffh);
  k_attn_cvt<<<2048, 256, 0, stream>>>(q_raw, k_buf, v_t, u_o, Wao, Wff, wcat);
  k_gemm2<<<2*(MROWS/128)*(DIMD/128), 256, 0, stream>>>(u_o, ffh, wcat, out, part);
  k_addout<<<2048, 256, 0, stream>>>(out, part, (long)MROWS*DIMD/4);
}